// Round 5
// baseline (196.082 us; speedup 1.0000x reference)
//
#include <hip/hip_runtime.h>
#include <math.h>

// Problem constants (B=4, S=4096, H=4096, E=64, top_k=8)
#define TOKENS 16384   // B*S
#define HDIM   4096
#define NEXP   64
#define TOPK   8

#define BM 16          // tokens per block
#define BK 32          // K-chunk
#define LDF 36         // LDS row stride in floats: 36 -> (4r+kq)%32 read pattern, 2-way max (free)
#define CHUNKS (HDIM / BK)

typedef double f64x4 __attribute__((ext_vector_type(4)));

// ---- fp64-MFMA GEMM, occupancy-optimized ----
// logits[t][e] = dot(hidden[t][:], weight[e][:]); fp64 accumulation via
// v_mfma_f64_16x16x4f64 => ordering matches the fp64 numpy reference.
// LDS holds fp32 (half footprint); cvt to f64 feeds the MFMA (2 cvt per
// 64-cycle MFMA, negligible). grid=1024 -> 4 blocks/CU -> 4 waves/SIMD so
// barrier/staging phases of one block overlap MFMA of the others.
// C/D layout self-calibrated by probe MFMAs (any bijective layout works).
__global__ __launch_bounds__(256) void router_gemm_mfma(const float* __restrict__ hid,
                                                        const float* __restrict__ wgt,
                                                        float* __restrict__ logits) {
    __shared__ float As[2][BM * LDF];     // 2 x 576  floats = 4.6 KB
    __shared__ float Bs[2][NEXP * LDF];   // 2 x 2304 floats = 18.4 KB

    const int tid  = threadIdx.x;
    const int bm   = blockIdx.x * BM;
    const int wv   = tid >> 6;       // wave 0..3 -> experts wv*16..wv*16+15
    const int lane = tid & 63;
    const int r    = lane & 15;      // A-row / B-col free index
    const int kq   = lane >> 4;      // k-slot within K=4

    // ---- C/D layout self-calibration (2 probe MFMAs) ----
    f64x4 rowp = {0., 0., 0., 0.};
    f64x4 colp = {0., 0., 0., 0.};
    rowp = __builtin_amdgcn_mfma_f64_16x16x4f64((double)r, 1.0, rowp, 0, 0, 0);
    colp = __builtin_amdgcn_mfma_f64_16x16x4f64(1.0, (double)r, colp, 0, 0, 0);
    int drow[4], dcol[4];
#pragma unroll
    for (int j = 0; j < 4; ++j) {
        drow[j] = (int)(rowp[j] * 0.25 + 0.5);   // exact multiples of 4
        dcol[j] = (int)(colp[j] * 0.25 + 0.5);
    }

    f64x4 acc = {0., 0., 0., 0.};

    // staging decomposition:
    //  A: 16 rows x 8 float4 = 128 float4 -> threads 0..127, row=t>>3, f=t&7
    //  B: 64 rows x 8 float4 = 512 float4 -> 2 per thread, rows t>>3 and 32+(t>>3)
    const int arow = tid >> 3;           // 0..31 (A uses <16)
    const int af   = tid & 7;
    const int brow = tid >> 3;           // 0..31 ; second row = brow+32
    const int bf   = tid & 7;

    float4 pa, pb0, pb1;

    // ---- prologue: chunk 0 -> LDS[0] ----
    if (tid < 128) pa = *reinterpret_cast<const float4*>(&hid[(size_t)(bm + arow) * HDIM + af * 4]);
    pb0 = *reinterpret_cast<const float4*>(&wgt[(size_t)brow * HDIM + bf * 4]);
    pb1 = *reinterpret_cast<const float4*>(&wgt[(size_t)(brow + 32) * HDIM + bf * 4]);
    if (tid < 128) *reinterpret_cast<float4*>(&As[0][arow * LDF + af * 4]) = pa;
    *reinterpret_cast<float4*>(&Bs[0][brow * LDF + bf * 4])        = pb0;
    *reinterpret_cast<float4*>(&Bs[0][(brow + 32) * LDF + bf * 4]) = pb1;

    int cur = 0;
    for (int c = 0; c < CHUNKS; ++c) {
        __syncthreads();   // LDS[cur] fully written

        // prefetch next chunk into registers (hides under MFMA cluster)
        if (c + 1 < CHUNKS) {
            const int k0n = (c + 1) * BK;
            if (tid < 128) pa = *reinterpret_cast<const float4*>(&hid[(size_t)(bm + arow) * HDIM + k0n + af * 4]);
            pb0 = *reinterpret_cast<const float4*>(&wgt[(size_t)brow * HDIM + k0n + bf * 4]);
            pb1 = *reinterpret_cast<const float4*>(&wgt[(size_t)(brow + 32) * HDIM + k0n + bf * 4]);
        }

        // compute: 8 K4-steps, 1 MFMA each (per-wave 16 tokens x 16 experts)
        const float* Ab = &As[cur][r * LDF + kq];
        const float* Bb = &Bs[cur][(wv * 16 + r) * LDF + kq];
#pragma unroll
        for (int ks = 0; ks < 8; ++ks) {
            double a = (double)Ab[ks * 4];
            double b = (double)Bb[ks * 4];
            acc = __builtin_amdgcn_mfma_f64_16x16x4f64(a, b, acc, 0, 0, 0);
        }

        // write prefetched chunk to the other buffer (read only after next barrier)
        if (c + 1 < CHUNKS) {
            if (tid < 128) *reinterpret_cast<float4*>(&As[cur ^ 1][arow * LDF + af * 4]) = pa;
            *reinterpret_cast<float4*>(&Bs[cur ^ 1][brow * LDF + bf * 4])        = pb0;
            *reinterpret_cast<float4*>(&Bs[cur ^ 1][(brow + 32) * LDF + bf * 4]) = pb1;
        }
        cur ^= 1;
    }

    // ---- epilogue: probe-derived scatter ----
#pragma unroll
    for (int j = 0; j < 4; ++j) {
        const int row = bm + drow[j];
        const int col = wv * 16 + dcol[j];
        logits[(size_t)row * NEXP + col] = (float)acc[j];
    }
}

// ---------------- top-k + softmax: one wave (64 lanes) per token ----------------
__global__ __launch_bounds__(256) void topk_softmax(const float* __restrict__ logits,
                                                    float* __restrict__ out_idx,
                                                    float* __restrict__ out_w) {
    const int wave  = threadIdx.x >> 6;              // 0..3
    const int lane  = threadIdx.x & 63;
    const int token = blockIdx.x * 4 + wave;
    if (token >= TOKENS) return;

    float v = logits[(size_t)token * NEXP + lane];

    float myval = 0.f;
    int   myidx = 0;
    float max0  = 0.f;

#pragma unroll
    for (int k = 0; k < TOPK; ++k) {
        float bv = v;
        int   bi = lane;
#pragma unroll
        for (int off = 32; off > 0; off >>= 1) {   // argmax, tie -> lower index
            float ov = __shfl_xor(bv, off);
            int   oi = __shfl_xor(bi, off);
            if (ov > bv || (ov == bv && oi < bi)) { bv = ov; bi = oi; }
        }
        if (k == 0) max0 = bv;
        if (lane == k) { myval = bv; myidx = bi; }
        if (lane == bi) v = -INFINITY;
    }

    float e = (lane < TOPK) ? expf(myval - max0) : 0.f;
    float s = e;
#pragma unroll
    for (int off = 4; off > 0; off >>= 1) s += __shfl_xor(s, off);

    if (lane < TOPK) {
        size_t o = (size_t)token * TOPK + lane;
        out_idx[o] = (float)myidx;
        out_w[o]   = e / s;
    }
}

extern "C" void kernel_launch(void* const* d_in, const int* in_sizes, int n_in,
                              void* d_out, int out_size, void* d_ws, size_t ws_size,
                              hipStream_t stream) {
    const float* hid = (const float*)d_in[0];
    const float* wgt = (const float*)d_in[1];

    float* logits  = (float*)d_out;
    float* out_idx = logits + (size_t)TOKENS * NEXP;
    float* out_w   = out_idx + (size_t)TOKENS * TOPK;

    router_gemm_mfma<<<TOKENS / BM, 256, 0, stream>>>(hid, wgt, logits);
    topk_softmax<<<TOKENS / 4, 256, 0, stream>>>(logits, out_idx, out_w);
}

// Round 6
// 188.116 us; speedup vs baseline: 1.0423x; 1.0423x over previous
//
#include <hip/hip_runtime.h>
#include <math.h>

// Problem constants (B=4, S=4096, H=4096, E=64, top_k=8)
#define TOKENS 16384   // B*S
#define HDIM   4096
#define NEXP   64
#define TOPK   8

#define BM 16          // tokens per block
#define BK 32          // K-chunk
#define LDF 36         // LDS row stride in floats -> compute-read bank (4r+kq+4ks)%32, 2-way max (free)
#define CHUNKS (HDIM / BK)

typedef double f64x4 __attribute__((ext_vector_type(4)));

// ---- fp64-MFMA GEMM, 2-deep software pipeline ----
// logits[t][e] = dot(hidden[t][:], weight[e][:]); fp64 accumulation via
// v_mfma_f64_16x16x4f64 => top-k ordering matches the fp64 numpy reference.
// Pipeline: at chunk c we issue global loads for chunk c+2 (register set X)
// and write register set Y (chunk c+1, issued a full chunk ago -> ~900cy HBM
// latency already elapsed) into the spare LDS buffer. The vmcnt wait before
// the LDS write is therefore ~free, unlike the 1-deep version (58.7% MfmaUtil,
// ~400cy stall/chunk). Accumulation order unchanged vs the passing round.
// C/D layout self-calibrated by probe MFMAs (any bijective layout works).
__global__ __launch_bounds__(256) void router_gemm_mfma(const float* __restrict__ hid,
                                                        const float* __restrict__ wgt,
                                                        float* __restrict__ logits) {
    __shared__ float As[2][BM * LDF];     // 2 x 576  floats = 4.6 KB
    __shared__ float Bs[2][NEXP * LDF];   // 2 x 2304 floats = 18.4 KB

    const int tid  = threadIdx.x;
    const int bm   = blockIdx.x * BM;
    const int wv   = tid >> 6;       // wave 0..3 -> experts wv*16..wv*16+15
    const int lane = tid & 63;
    const int r    = lane & 15;      // A-row / B-col free index
    const int kq   = lane >> 4;      // k-slot within K=4

    // ---- C/D layout self-calibration (2 probe MFMAs) ----
    f64x4 rowp = {0., 0., 0., 0.};
    f64x4 colp = {0., 0., 0., 0.};
    rowp = __builtin_amdgcn_mfma_f64_16x16x4f64((double)r, 1.0, rowp, 0, 0, 0);
    colp = __builtin_amdgcn_mfma_f64_16x16x4f64(1.0, (double)r, colp, 0, 0, 0);
    int drow[4], dcol[4];
#pragma unroll
    for (int j = 0; j < 4; ++j) {
        drow[j] = (int)(rowp[j] * 0.25 + 0.5);   // exact multiples of 4
        dcol[j] = (int)(colp[j] * 0.25 + 0.5);
    }

    f64x4 acc = {0., 0., 0., 0.};

    // staging decomposition:
    //  A: 16 rows x 8 float4 -> threads 0..127 (row=t>>3, f=t&7)
    //  B: 64 rows x 8 float4 -> 2 per thread (rows t>>3 and 32+(t>>3))
    const int arow = tid >> 3;
    const int af   = tid & 7;
    const int brow = tid >> 3;
    const int bf   = tid & 7;

    float4 pa0, pb00, pb10;   // register set 0
    float4 pa1, pb01, pb11;   // register set 1

#define LOAD_SET(PA, PB0, PB1, K0) do { \
        if (tid < 128) PA = *reinterpret_cast<const float4*>(&hid[(size_t)(bm + arow) * HDIM + (K0) + af * 4]); \
        PB0 = *reinterpret_cast<const float4*>(&wgt[(size_t)brow * HDIM + (K0) + bf * 4]); \
        PB1 = *reinterpret_cast<const float4*>(&wgt[(size_t)(brow + 32) * HDIM + (K0) + bf * 4]); \
    } while (0)

#define WRITE_SET(PA, PB0, PB1, BUF) do { \
        if (tid < 128) *reinterpret_cast<float4*>(&As[BUF][arow * LDF + af * 4]) = PA; \
        *reinterpret_cast<float4*>(&Bs[BUF][brow * LDF + bf * 4]) = PB0; \
        *reinterpret_cast<float4*>(&Bs[BUF][(brow + 32) * LDF + bf * 4]) = PB1; \
    } while (0)

#define COMPUTE(BUF) do { \
        const float* Ab = &As[BUF][r * LDF + kq]; \
        const float* Bb = &Bs[BUF][(wv * 16 + r) * LDF + kq]; \
        _Pragma("unroll") \
        for (int ks = 0; ks < 8; ++ks) { \
            acc = __builtin_amdgcn_mfma_f64_16x16x4f64((double)Ab[ks * 4], (double)Bb[ks * 4], acc, 0, 0, 0); \
        } \
    } while (0)

    // ---- prologue ----
    LOAD_SET(pa0, pb00, pb10, 0);        // chunk 0
    WRITE_SET(pa0, pb00, pb10, 0);       // -> LDS[0] (vmcnt auto-inserted)
    LOAD_SET(pa1, pb01, pb11, BK);       // chunk 1, left in flight

    // ---- main loop, 2 chunks per iteration (CHUNKS = 128, even) ----
    for (int c = 0; c < CHUNKS; c += 2) {
        __syncthreads();                                   // LDS[0] = chunk c ready
        if (c + 2 < CHUNKS) LOAD_SET(pa0, pb00, pb10, (c + 2) * BK);  // issue c+2
        COMPUTE(0);                                        // chunk c
        WRITE_SET(pa1, pb01, pb11, 1);                     // chunk c+1 -> LDS[1] (loads long landed)
        __syncthreads();                                   // LDS[1] = chunk c+1 ready
        if (c + 3 < CHUNKS) LOAD_SET(pa1, pb01, pb11, (c + 3) * BK);  // issue c+3
        COMPUTE(1);                                        // chunk c+1
        if (c + 2 < CHUNKS) WRITE_SET(pa0, pb00, pb10, 0); // chunk c+2 -> LDS[0]
    }

#undef LOAD_SET
#undef WRITE_SET
#undef COMPUTE

    // ---- epilogue: probe-derived scatter ----
#pragma unroll
    for (int j = 0; j < 4; ++j) {
        const int row = bm + drow[j];
        const int col = wv * 16 + dcol[j];
        logits[(size_t)row * NEXP + col] = (float)acc[j];
    }
}

// ---------------- top-k + softmax: one wave (64 lanes) per token ----------------
__global__ __launch_bounds__(256) void topk_softmax(const float* __restrict__ logits,
                                                    float* __restrict__ out_idx,
                                                    float* __restrict__ out_w) {
    const int wave  = threadIdx.x >> 6;              // 0..3
    const int lane  = threadIdx.x & 63;
    const int token = blockIdx.x * 4 + wave;
    if (token >= TOKENS) return;

    float v = logits[(size_t)token * NEXP + lane];

    float myval = 0.f;
    int   myidx = 0;
    float max0  = 0.f;

#pragma unroll
    for (int k = 0; k < TOPK; ++k) {
        float bv = v;
        int   bi = lane;
#pragma unroll
        for (int off = 32; off > 0; off >>= 1) {   // argmax, tie -> lower index
            float ov = __shfl_xor(bv, off);
            int   oi = __shfl_xor(bi, off);
            if (ov > bv || (ov == bv && oi < bi)) { bv = ov; bi = oi; }
        }
        if (k == 0) max0 = bv;
        if (lane == k) { myval = bv; myidx = bi; }
        if (lane == bi) v = -INFINITY;
    }

    float e = (lane < TOPK) ? expf(myval - max0) : 0.f;
    float s = e;
#pragma unroll
    for (int off = 4; off > 0; off >>= 1) s += __shfl_xor(s, off);

    if (lane < TOPK) {
        size_t o = (size_t)token * TOPK + lane;
        out_idx[o] = (float)myidx;
        out_w[o]   = e / s;
    }
}

extern "C" void kernel_launch(void* const* d_in, const int* in_sizes, int n_in,
                              void* d_out, int out_size, void* d_ws, size_t ws_size,
                              hipStream_t stream) {
    const float* hid = (const float*)d_in[0];
    const float* wgt = (const float*)d_in[1];

    float* logits  = (float*)d_out;
    float* out_idx = logits + (size_t)TOKENS * NEXP;
    float* out_w   = out_idx + (size_t)TOKENS * TOPK;

    router_gemm_mfma<<<TOKENS / BM, 256, 0, stream>>>(hid, wgt, logits);
    topk_softmax<<<TOKENS / 4, 256, 0, stream>>>(logits, out_idx, out_w);
}